// Round 3
// baseline (2365.745 us; speedup 1.0000x reference)
//
#include <hip/hip_runtime.h>

#define NEGV (-10000.0f)

static constexpr int Bb    = 128;
static constexpr int Tt    = 512;
static constexpr int Mrows = Bb * Tt;   // 65536
static constexpr int Hh    = 50;
static constexpr int Ncols = 400;       // both directions stacked
static constexpr int START = 5;

__device__ __forceinline__ float fsig(float x) {
    return 1.0f / (1.0f + __expf(-x));
}
__device__ __forceinline__ float ftanh(float x) {
    return 2.0f / (1.0f + __expf(-2.0f * x)) - 1.0f;
}

// ---------------------------------------------------------------------------
// GEMM: C[M,N] = A[M,K] @ W[N,K]^T + bias[N]
// A rows optionally gathered through idx (embedding lookup for layer 0).
// 64x64 tile, BK=16, 256 threads, 4x4 microtile.
// ---------------------------------------------------------------------------
template <bool GATHER>
__global__ __launch_bounds__(256) void gemm_xg(
    const float* __restrict__ A, const int* __restrict__ idx,
    const float* __restrict__ W, const float* __restrict__ bias,
    float* __restrict__ C, int M, int N, int K)
{
    __shared__ __align__(16) float As[16][68];
    __shared__ __align__(16) float Bs[16][68];

    const int tid = threadIdx.x;
    const int m0 = blockIdx.x * 64;
    const int n0 = blockIdx.y * 64;

    const int lm = tid >> 2;          // 0..63
    const int lk = (tid & 3) * 4;     // 0,4,8,12
    const int col = (tid & 15) * 4;   // 0..60
    const int row = (tid >> 4) * 4;   // 0..60

    float acc[4][4] = {};

    const long arow = m0 + lm;
    const long asrc = GATHER ? (long)idx[arow] : arow;
    const float* Aptr = A + asrc * K;
    const bool wvalid = (n0 + lm) < N;
    const float* Wptr = W + (long)(n0 + lm) * K;

    for (int k0 = 0; k0 < K; k0 += 16) {
        const int k = k0 + lk;
        float4 av = make_float4(0.f, 0.f, 0.f, 0.f);
        float4 bv = make_float4(0.f, 0.f, 0.f, 0.f);
        if (k + 3 < K) {
            av = *(const float4*)(Aptr + k);
        } else {
            if (k + 0 < K) av.x = Aptr[k + 0];
            if (k + 1 < K) av.y = Aptr[k + 1];
            if (k + 2 < K) av.z = Aptr[k + 2];
            if (k + 3 < K) av.w = Aptr[k + 3];
        }
        if (wvalid) {
            if (k + 3 < K) {
                bv = *(const float4*)(Wptr + k);
            } else {
                if (k + 0 < K) bv.x = Wptr[k + 0];
                if (k + 1 < K) bv.y = Wptr[k + 1];
                if (k + 2 < K) bv.z = Wptr[k + 2];
                if (k + 3 < K) bv.w = Wptr[k + 3];
            }
        }
        __syncthreads();
        As[lk + 0][lm] = av.x; As[lk + 1][lm] = av.y;
        As[lk + 2][lm] = av.z; As[lk + 3][lm] = av.w;
        Bs[lk + 0][lm] = bv.x; Bs[lk + 1][lm] = bv.y;
        Bs[lk + 2][lm] = bv.z; Bs[lk + 3][lm] = bv.w;
        __syncthreads();
        #pragma unroll
        for (int kk = 0; kk < 16; ++kk) {
            float4 a = *(const float4*)(&As[kk][row]);
            float4 b = *(const float4*)(&Bs[kk][col]);
            acc[0][0] += a.x * b.x; acc[0][1] += a.x * b.y; acc[0][2] += a.x * b.z; acc[0][3] += a.x * b.w;
            acc[1][0] += a.y * b.x; acc[1][1] += a.y * b.y; acc[1][2] += a.y * b.z; acc[1][3] += a.y * b.w;
            acc[2][0] += a.z * b.x; acc[2][1] += a.z * b.y; acc[2][2] += a.z * b.z; acc[2][3] += a.z * b.w;
            acc[3][0] += a.w * b.x; acc[3][1] += a.w * b.y; acc[3][2] += a.w * b.z; acc[3][3] += a.w * b.w;
        }
    }

    #pragma unroll
    for (int ii = 0; ii < 4; ++ii) {
        const long crow = m0 + row + ii;
        const int c0i = n0 + col;
        if (c0i + 3 < N) {
            float4 v;
            v.x = acc[ii][0] + bias[c0i + 0];
            v.y = acc[ii][1] + bias[c0i + 1];
            v.z = acc[ii][2] + bias[c0i + 2];
            v.w = acc[ii][3] + bias[c0i + 3];
            *(float4*)(C + crow * N + c0i) = v;
        } else {
            #pragma unroll
            for (int jj = 0; jj < 4; ++jj) {
                int cc = c0i + jj;
                if (cc < N) C[crow * N + cc] = acc[ii][jj] + bias[cc];
            }
        }
    }
}

// ---------------------------------------------------------------------------
// LSTM scan: ONE WAVE per (batch row, direction); zero barriers in the loop.
// All 4 gate-weight matrices live in LDS in a transposed, conflict-free
// layout wT[gate][k4][unit][4]: per step, lane u does 52 lane-indexed
// ds_read_b128 (consecutive lanes -> consecutive 16B: conflict-free) plus
// 13 broadcast h reads. Register pressure ~50 VGPRs: structurally
// spill-proof (rounds 1-2 showed per-lane weight arrays always spill).
// ---------------------------------------------------------------------------
__global__ __launch_bounds__(64) void lstm_scan(
    const float* __restrict__ xg,     // [M,400] (bias already added)
    const float* __restrict__ w_hh,   // [2,200,50]
    const float* __restrict__ h0,     // layer base: [2,B,50]
    const float* __restrict__ c0,
    float* __restrict__ xout)         // [M,100], col = dir*50+k
{
    const int b    = blockIdx.x & 127;
    const int dir  = blockIdx.x >> 7;
    const int lane = threadIdx.x;

    __shared__ __align__(16) float wT[4][13][50][4];  // 41.6 KB
    __shared__ __align__(16) float hs[52];

    const int iu = (lane < 50) ? lane : 0;

    // ---- one-time: transpose weights into LDS (row-per-lane) ----
    {
        const float* wb = w_hh + (long)dir * 200 * 50;
        for (int r = lane; r < 200; r += 64) {
            const int g = r / 50;
            const int u = r % 50;
            const float* wr = wb + (long)r * 50;
            #pragma unroll
            for (int j = 0; j < 50; ++j) wT[g][j >> 2][u][j & 3] = wr[j];
            wT[g][12][u][2] = 0.f;
            wT[g][12][u][3] = 0.f;
        }
    }

    float c = 0.f;
    if (lane < 50) {
        c        = c0[(long)dir * Bb * Hh + (long)b * Hh + lane];
        hs[lane] = h0[(long)dir * Bb * Hh + (long)b * Hh + lane];
    } else if (lane < 52) {
        hs[lane] = 0.f;
    }
    __syncthreads();   // once, before the loop (single wave, but cheap)

    const long rowbase = (long)b * Tt;
    const float* xp = xg + rowbase * 400 + dir * 200 + iu;   // lane base
    float* op = xout + rowbase * 100 + dir * 50 + iu;

    // depth-3 prefetch queue of the 4 xg gate values
    float q0[4], q1[4], q2[4];
    {
        const int t0 = dir ? (Tt - 1) : 0;
        const int t1 = dir ? (Tt - 2) : 1;
        const int t2 = dir ? (Tt - 3) : 2;
        const float* p;
        p = xp + (long)t0 * 400; q0[0]=p[0]; q0[1]=p[50]; q0[2]=p[100]; q0[3]=p[150];
        p = xp + (long)t1 * 400; q1[0]=p[0]; q1[1]=p[50]; q1[2]=p[100]; q1[3]=p[150];
        p = xp + (long)t2 * 400; q2[0]=p[0]; q2[1]=p[50]; q2[2]=p[100]; q2[3]=p[150];
    }

    for (int s = 0; s < Tt; ++s) {
        const int tt = dir ? (Tt - 1 - s) : s;

        float pi0 = q0[0], pf0 = q0[1], pg0 = q0[2], po0 = q0[3];
        float pi1 = 0.f,   pf1 = 0.f,   pg1 = 0.f,   po1 = 0.f;
        q0[0]=q1[0]; q0[1]=q1[1]; q0[2]=q1[2]; q0[3]=q1[3];
        q1[0]=q2[0]; q1[1]=q2[1]; q1[2]=q2[2]; q1[3]=q2[3];
        if (s + 3 < Tt) {                         // wave-uniform condition
            const int tn = dir ? (Tt - 1 - (s + 3)) : (s + 3);
            const float* p = xp + (long)tn * 400;
            q2[0]=p[0]; q2[1]=p[50]; q2[2]=p[100]; q2[3]=p[150];
        }

        #pragma unroll
        for (int q = 0; q < 13; ++q) {
            const float4 hv = *(const float4*)(&hs[4 * q]);          // broadcast
            const float4 a  = *(const float4*)(&wT[0][q][iu][0]);    // lane-indexed
            const float4 bb = *(const float4*)(&wT[1][q][iu][0]);
            const float4 cc = *(const float4*)(&wT[2][q][iu][0]);
            const float4 dd = *(const float4*)(&wT[3][q][iu][0]);
            pi0 += a.x  * hv.x + a.z  * hv.z;  pi1 += a.y  * hv.y + a.w  * hv.w;
            pf0 += bb.x * hv.x + bb.z * hv.z;  pf1 += bb.y * hv.y + bb.w * hv.w;
            pg0 += cc.x * hv.x + cc.z * hv.z;  pg1 += cc.y * hv.y + cc.w * hv.w;
            po0 += dd.x * hv.x + dd.z * hv.z;  po1 += dd.y * hv.y + dd.w * hv.w;
        }

        const float gi = fsig(pi0 + pi1);
        const float gf = fsig(pf0 + pf1);
        const float gc = ftanh(pg0 + pg1);
        const float go = fsig(po0 + po1);
        c = gf * c + gi * gc;
        const float h = go * ftanh(c);

        if (lane < 50) {
            hs[lane] = h;                      // ds_write; next iter's ds_read
            op[(long)tt * 100] = h;            // ordered within the wave
        }
    }
}

// ---------------------------------------------------------------------------
// feats[row, i] = (x[row,:] . w_tag[i,:] + b_tag[i]) * mask[row], padded to 8
// ---------------------------------------------------------------------------
__global__ __launch_bounds__(256) void feats_kernel(
    const float* __restrict__ x,      // [M,100]
    const float* __restrict__ w_tag,  // [7,100]
    const float* __restrict__ b_tag,  // [7]
    const float* __restrict__ mask,   // [M]
    float* __restrict__ feats)        // [M,8]
{
    const int gid = blockIdx.x * 256 + threadIdx.x;
    const int row = gid >> 3;
    const int i   = gid & 7;
    if (row >= Mrows) return;
    if (i == 7) { feats[(long)row * 8 + 7] = 0.f; return; }
    const float4* xr = (const float4*)(x + (long)row * 100);
    const float4* wr = (const float4*)(w_tag + (long)i * 100);
    float acc = b_tag[i];
    #pragma unroll
    for (int q = 0; q < 25; ++q) {
        float4 a = xr[q];
        float4 b = wr[q];
        acc += a.x * b.x + a.y * b.y + a.z * b.z + a.w * b.w;
    }
    feats[(long)row * 8 + i] = acc * mask[row];
}

// ---------------------------------------------------------------------------
// Viterbi forward. 8 lanes per batch row (i = lane&7, i<7 active).
// Packs the 7 backpointers of a step into one u32 (3 bits each), stored [T][B].
// ---------------------------------------------------------------------------
__global__ __launch_bounds__(64) void viterbi_fwd(
    const float* __restrict__ feats,   // [M,8]
    const float* __restrict__ trans,   // [7,7]
    unsigned int* __restrict__ bptrw,  // [T*B]
    float* __restrict__ best_score,    // [B] -> d_out
    int* __restrict__ best_tag)        // [B] -> ws
{
    const int lane = threadIdx.x;
    const int sub  = lane >> 3;
    const int i    = lane & 7;
    const int b    = blockIdx.x * 8 + sub;
    const int base = lane & 56;

    float tr[7];
    #pragma unroll
    for (int j = 0; j < 7; ++j) tr[j] = (i < 7) ? trans[i * 7 + j] : -1e30f;

    float score = (i == START) ? 0.0f : NEGV;
    const long fb = (long)b * Tt;

    float featc = feats[(fb + 0) * 8 + i];
    for (int t = 0; t < Tt; ++t) {
        float featn = (t + 1 < Tt) ? feats[(fb + t + 1) * 8 + i] : 0.f;
        float best = -3.4e38f;
        int bp = 0;
        #pragma unroll
        for (int j = 0; j < 7; ++j) {
            float sj = __shfl(score, base | j, 64);
            float m = sj + tr[j];
            if (m > best) { best = m; bp = j; }   // strict > : first-tie like argmax
        }
        if (i < 7) score = best + featc;
        unsigned v = (i < 7) ? ((unsigned)bp << (3 * i)) : 0u;
        v |= __shfl_xor(v, 1, 64);
        v |= __shfl_xor(v, 2, 64);
        v |= __shfl_xor(v, 4, 64);
        if (i == 0) bptrw[(long)t * Bb + b] = v;
        featc = featn;
    }

    float bestv = score;
    int bt = 0;
    #pragma unroll
    for (int j = 1; j < 7; ++j) {
        float sj = __shfl(score, base | j, 64);
        if (i == 0 && sj > bestv) { bestv = sj; bt = j; }
    }
    if (i == 0) {
        best_score[b] = bestv;
        best_tag[b]   = bt;
    }
}

// ---------------------------------------------------------------------------
// Backtrace: tags[t-1] = bptr[t][tags[t]]  (bptr stored [T][B]: coalesced,
// and the load address is tag-independent -> loads pipeline freely)
// ---------------------------------------------------------------------------
__global__ __launch_bounds__(128) void backtrack(
    const unsigned int* __restrict__ bptrw,
    const int* __restrict__ best_tag,
    float* __restrict__ out_tags)   // d_out + 128, [B,T]
{
    const int b = threadIdx.x;
    if (b >= Bb) return;
    const long fb = (long)b * Tt;
    int tag = best_tag[b];
    out_tags[fb + Tt - 1] = (float)tag;
    #pragma unroll 8
    for (int t = Tt - 1; t >= 1; --t) {
        unsigned w = bptrw[(long)t * Bb + b];
        tag = (w >> (3 * tag)) & 7;
        out_tags[fb + t - 1] = (float)tag;
    }
}

// ---------------------------------------------------------------------------
extern "C" void kernel_launch(void* const* d_in, const int* in_sizes, int n_in,
                              void* d_out, int out_size, void* d_ws, size_t ws_size,
                              hipStream_t stream)
{
    const int*   sent    = (const int*)  d_in[0];
    const float* mask    = (const float*)d_in[1];
    const float* emb     = (const float*)d_in[2];
    const float* h0      = (const float*)d_in[3];
    const float* c0      = (const float*)d_in[4];
    const float* w_ih_l0 = (const float*)d_in[5];
    const float* w_hh_l0 = (const float*)d_in[6];
    const float* b_l0    = (const float*)d_in[7];
    const float* w_ih_l1 = (const float*)d_in[8];
    const float* w_hh_l1 = (const float*)d_in[9];
    const float* b_l1    = (const float*)d_in[10];
    const float* w_ih_l2 = (const float*)d_in[11];
    const float* w_hh_l2 = (const float*)d_in[12];
    const float* b_l2    = (const float*)d_in[13];
    const float* w_tag   = (const float*)d_in[14];
    const float* b_tag   = (const float*)d_in[15];
    const float* trans   = (const float*)d_in[16];

    float* out = (float*)d_out;

    char* ws = (char*)d_ws;
    const long xg_bytes = (long)Mrows * Ncols * 4;        // 104,857,600
    const long xa_bytes = (long)Mrows * 100 * 4;          //  26,214,400
    float*    xg    = (float*)(ws);
    float*    xa    = (float*)(ws + xg_bytes);
    float*    xb    = (float*)(ws + xg_bytes + xa_bytes);
    float*    feats = (float*)(ws + xg_bytes + 2 * xa_bytes);
    unsigned* bptrw = (unsigned*)(ws + xg_bytes + 2 * xa_bytes + (long)Mrows * 8 * 4);
    int*      btag  = (int*)(ws + xg_bytes + 2 * xa_bytes + (long)Mrows * 8 * 4 + (long)Bb * Tt * 4);

    dim3 gridG(Mrows / 64, (Ncols + 63) / 64);

    // layer 0 (embedding gathered inside the GEMM)
    gemm_xg<true><<<gridG, 256, 0, stream>>>(emb, sent, w_ih_l0, b_l0, xg, Mrows, Ncols, 300);
    lstm_scan<<<256, 64, 0, stream>>>(xg, w_hh_l0, h0 + 0 * Bb * Hh, c0 + 0 * Bb * Hh, xa);

    // layer 1
    gemm_xg<false><<<gridG, 256, 0, stream>>>(xa, nullptr, w_ih_l1, b_l1, xg, Mrows, Ncols, 100);
    lstm_scan<<<256, 64, 0, stream>>>(xg, w_hh_l1, h0 + 2 * Bb * Hh, c0 + 2 * Bb * Hh, xb);

    // layer 2
    gemm_xg<false><<<gridG, 256, 0, stream>>>(xb, nullptr, w_ih_l2, b_l2, xg, Mrows, Ncols, 100);
    lstm_scan<<<256, 64, 0, stream>>>(xg, w_hh_l2, h0 + 4 * Bb * Hh, c0 + 4 * Bb * Hh, xa);

    // tag projection + viterbi + backtrace
    feats_kernel<<<Mrows * 8 / 256, 256, 0, stream>>>(xa, w_tag, b_tag, mask, feats);
    viterbi_fwd<<<Bb / 8, 64, 0, stream>>>(feats, trans, bptrw, out, btag);
    backtrack<<<1, 128, 0, stream>>>(bptrw, btag, out + Bb);
}

// Round 4
// 1577.922 us; speedup vs baseline: 1.4993x; 1.4993x over previous
//
#include <hip/hip_runtime.h>

#define NEGV (-10000.0f)

static constexpr int Bb    = 128;
static constexpr int Tt    = 512;
static constexpr int Mrows = Bb * Tt;   // 65536
static constexpr int Hh    = 50;
static constexpr int Ncols = 400;       // both directions stacked
static constexpr int START = 5;

__device__ __forceinline__ float fsig(float x) {
    return __builtin_amdgcn_rcpf(1.0f + __expf(-x));
}
__device__ __forceinline__ float ftanh(float x) {
    return 2.0f * __builtin_amdgcn_rcpf(1.0f + __expf(-2.0f * x)) - 1.0f;
}

// ---------------------------------------------------------------------------
// GEMM: C[M,N] = A[M,K] @ W[N,K]^T + bias[N]   (unchanged, known-good)
// ---------------------------------------------------------------------------
template <bool GATHER>
__global__ __launch_bounds__(256) void gemm_xg(
    const float* __restrict__ A, const int* __restrict__ idx,
    const float* __restrict__ W, const float* __restrict__ bias,
    float* __restrict__ C, int M, int N, int K)
{
    __shared__ __align__(16) float As[16][68];
    __shared__ __align__(16) float Bs[16][68];

    const int tid = threadIdx.x;
    const int m0 = blockIdx.x * 64;
    const int n0 = blockIdx.y * 64;

    const int lm = tid >> 2;          // 0..63
    const int lk = (tid & 3) * 4;     // 0,4,8,12
    const int col = (tid & 15) * 4;   // 0..60
    const int row = (tid >> 4) * 4;   // 0..60

    float acc[4][4] = {};

    const long arow = m0 + lm;
    const long asrc = GATHER ? (long)idx[arow] : arow;
    const float* Aptr = A + asrc * K;
    const bool wvalid = (n0 + lm) < N;
    const float* Wptr = W + (long)(n0 + lm) * K;

    for (int k0 = 0; k0 < K; k0 += 16) {
        const int k = k0 + lk;
        float4 av = make_float4(0.f, 0.f, 0.f, 0.f);
        float4 bv = make_float4(0.f, 0.f, 0.f, 0.f);
        if (k + 3 < K) {
            av = *(const float4*)(Aptr + k);
        } else {
            if (k + 0 < K) av.x = Aptr[k + 0];
            if (k + 1 < K) av.y = Aptr[k + 1];
            if (k + 2 < K) av.z = Aptr[k + 2];
            if (k + 3 < K) av.w = Aptr[k + 3];
        }
        if (wvalid) {
            if (k + 3 < K) {
                bv = *(const float4*)(Wptr + k);
            } else {
                if (k + 0 < K) bv.x = Wptr[k + 0];
                if (k + 1 < K) bv.y = Wptr[k + 1];
                if (k + 2 < K) bv.z = Wptr[k + 2];
                if (k + 3 < K) bv.w = Wptr[k + 3];
            }
        }
        __syncthreads();
        As[lk + 0][lm] = av.x; As[lk + 1][lm] = av.y;
        As[lk + 2][lm] = av.z; As[lk + 3][lm] = av.w;
        Bs[lk + 0][lm] = bv.x; Bs[lk + 1][lm] = bv.y;
        Bs[lk + 2][lm] = bv.z; Bs[lk + 3][lm] = bv.w;
        __syncthreads();
        #pragma unroll
        for (int kk = 0; kk < 16; ++kk) {
            float4 a = *(const float4*)(&As[kk][row]);
            float4 b = *(const float4*)(&Bs[kk][col]);
            acc[0][0] += a.x * b.x; acc[0][1] += a.x * b.y; acc[0][2] += a.x * b.z; acc[0][3] += a.x * b.w;
            acc[1][0] += a.y * b.x; acc[1][1] += a.y * b.y; acc[1][2] += a.y * b.z; acc[1][3] += a.y * b.w;
            acc[2][0] += a.z * b.x; acc[2][1] += a.z * b.y; acc[2][2] += a.z * b.z; acc[2][3] += a.z * b.w;
            acc[3][0] += a.w * b.x; acc[3][1] += a.w * b.y; acc[3][2] += a.w * b.z; acc[3][3] += a.w * b.w;
        }
    }

    #pragma unroll
    for (int ii = 0; ii < 4; ++ii) {
        const long crow = m0 + row + ii;
        const int c0i = n0 + col;
        if (c0i + 3 < N) {
            float4 v;
            v.x = acc[ii][0] + bias[c0i + 0];
            v.y = acc[ii][1] + bias[c0i + 1];
            v.z = acc[ii][2] + bias[c0i + 2];
            v.w = acc[ii][3] + bias[c0i + 3];
            *(float4*)(C + crow * N + c0i) = v;
        } else {
            #pragma unroll
            for (int jj = 0; jj < 4; ++jj) {
                int cc = c0i + jj;
                if (cc < N) C[crow * N + cc] = acc[ii][jj] + bias[cc];
            }
        }
    }
}

// ---------------------------------------------------------------------------
// LSTM scan: 4 waves per (b,dir) chain. Gate-major: thread t<200 owns
// w_hh row t in 52 VGPRs (__launch_bounds__(256,1) -> 512-reg cap, no
// spill). ONE raw s_barrier per step (no vmcnt drain -> xg prefetch stays
// in flight). Cross-wave handoff is only pre[2][200] (double-buffered;
// WAR-safe: each wave's lgkmcnt(0) before barrier N+1 drains its step-N
// pre reads). Activations computed redundantly per wave (private c,
// private hs copy) so no h handoff is needed.
// ---------------------------------------------------------------------------
__device__ __forceinline__ void lstm_step(
    int tt, float xin, float* __restrict__ prew, const float* __restrict__ prer,
    const float* __restrict__ w, float* __restrict__ hm,
    float& c, int tid, int lane, int wv, float* __restrict__ op)
{
    if (tid < 200) {
        float s0 = xin, s1 = 0.f, s2 = 0.f, s3 = 0.f;
        #pragma unroll
        for (int q = 0; q < 13; ++q) {
            const float4 hv = *(const float4*)(hm + 4 * q);   // broadcast read
            s0 += w[4*q+0] * hv.x; s1 += w[4*q+1] * hv.y;
            s2 += w[4*q+2] * hv.z; s3 += w[4*q+3] * hv.w;
        }
        prew[tid] = (s0 + s1) + (s2 + s3);
    }
    // my pre-write (and last step's pre-reads) drained, then barrier.
    // NO vmcnt drain: global prefetch loads stay in flight.
    asm volatile("s_waitcnt lgkmcnt(0)\n\ts_barrier" ::: "memory");
    if (lane < 50) {
        const float pi = prer[lane];
        const float pf = prer[50 + lane];
        const float pg = prer[100 + lane];
        const float po = prer[150 + lane];
        const float gi = fsig(pi);
        const float gf = fsig(pf);
        const float gc = ftanh(pg);
        const float go = fsig(po);
        c = gf * c + gi * gc;
        const float h = go * ftanh(c);
        hm[lane] = h;                       // own-wave copy; ordered by lgkmcnt
        if (wv == 0) op[(long)tt * 100] = h;
    }
}

__global__ __launch_bounds__(256, 1) void lstm_scan(
    const float* __restrict__ xg,     // [M,400] (bias already added)
    const float* __restrict__ w_hh,   // [2,200,50]
    const float* __restrict__ h0,     // layer base: [2,B,50]
    const float* __restrict__ c0,
    float* __restrict__ xout)         // [M,100], col = dir*50+k
{
    const int b    = blockIdx.x & 127;
    const int dir  = blockIdx.x >> 7;
    const int tid  = threadIdx.x;
    const int lane = tid & 63;
    const int wv   = tid >> 6;

    __shared__ __align__(16) float hsw[4][56];   // per-wave h copy (row 16B-aligned)
    __shared__ float pre[2][200];                // double-buffered pre-gates

    const int gr = (tid < 200) ? tid : 199;      // gate row (clamped)

    float w[52];
    {
        const float2* wr = (const float2*)(w_hh + ((long)dir * 200 + gr) * 50);
        #pragma unroll
        for (int q = 0; q < 25; ++q) { float2 v = wr[q]; w[2*q] = v.x; w[2*q+1] = v.y; }
        w[50] = 0.f; w[51] = 0.f;
    }

    float* hm = &hsw[wv][0];
    float c = 0.f;
    if (lane < 50) {
        c        = c0[((long)dir * Bb + b) * Hh + lane];
        hm[lane] = h0[((long)dir * Bb + b) * Hh + lane];
    } else if (lane < 56) {
        hm[lane] = 0.f;
    }
    __syncthreads();   // once, before the loop

    const long rowbase = (long)b * Tt;
    const float* xbase = xg + rowbase * 400 + dir * 200 + gr;
    float* op = xout + rowbase * 100 + dir * 50 + lane;

    #define XLD(s) xbase[(long)(dir ? (Tt - 1 - (s)) : (s)) * 400]
    #define TTOF(s) (dir ? (Tt - 1 - (s)) : (s))

    float xc0 = XLD(0), xc1 = XLD(1), xc2 = XLD(2), xc3 = XLD(3);
    float xn0 = 0.f, xn1 = 0.f, xn2 = 0.f, xn3 = 0.f;

    for (int blk = 0; blk < Tt / 4; ++blk) {
        const int s0 = blk * 4;
        if (blk < Tt / 4 - 1) {   // prefetch next 4 steps (stays in flight)
            xn0 = XLD(s0 + 4); xn1 = XLD(s0 + 5);
            xn2 = XLD(s0 + 6); xn3 = XLD(s0 + 7);
        }
        lstm_step(TTOF(s0 + 0), xc0, pre[0], pre[0], w, hm, c, tid, lane, wv, op);
        lstm_step(TTOF(s0 + 1), xc1, pre[1], pre[1], w, hm, c, tid, lane, wv, op);
        lstm_step(TTOF(s0 + 2), xc2, pre[0], pre[0], w, hm, c, tid, lane, wv, op);
        lstm_step(TTOF(s0 + 3), xc3, pre[1], pre[1], w, hm, c, tid, lane, wv, op);
        xc0 = xn0; xc1 = xn1; xc2 = xn2; xc3 = xn3;
    }
    #undef XLD
    #undef TTOF
}

// ---------------------------------------------------------------------------
// feats[row, i] = (x[row,:] . w_tag[i,:] + b_tag[i]) * mask[row], padded to 8
// ---------------------------------------------------------------------------
__global__ __launch_bounds__(256) void feats_kernel(
    const float* __restrict__ x,      // [M,100]
    const float* __restrict__ w_tag,  // [7,100]
    const float* __restrict__ b_tag,  // [7]
    const float* __restrict__ mask,   // [M]
    float* __restrict__ feats)        // [M,8]
{
    const int gid = blockIdx.x * 256 + threadIdx.x;
    const int row = gid >> 3;
    const int i   = gid & 7;
    if (row >= Mrows) return;
    if (i == 7) { feats[(long)row * 8 + 7] = 0.f; return; }
    const float4* xr = (const float4*)(x + (long)row * 100);
    const float4* wr = (const float4*)(w_tag + (long)i * 100);
    float acc = b_tag[i];
    #pragma unroll
    for (int q = 0; q < 25; ++q) {
        float4 a = xr[q];
        float4 b = wr[q];
        acc += a.x * b.x + a.y * b.y + a.z * b.z + a.w * b.w;
    }
    feats[(long)row * 8 + i] = acc * mask[row];
}

// ---------------------------------------------------------------------------
// Viterbi forward. 8 lanes per batch row (i = lane&7, i<7 active).
// Packs the 7 backpointers of a step into one u32 (3 bits each), stored [T][B].
// ---------------------------------------------------------------------------
__global__ __launch_bounds__(64) void viterbi_fwd(
    const float* __restrict__ feats,   // [M,8]
    const float* __restrict__ trans,   // [7,7]
    unsigned int* __restrict__ bptrw,  // [T*B]
    float* __restrict__ best_score,    // [B] -> d_out
    int* __restrict__ best_tag)        // [B] -> ws
{
    const int lane = threadIdx.x;
    const int sub  = lane >> 3;
    const int i    = lane & 7;
    const int b    = blockIdx.x * 8 + sub;
    const int base = lane & 56;

    float tr[7];
    #pragma unroll
    for (int j = 0; j < 7; ++j) tr[j] = (i < 7) ? trans[i * 7 + j] : -1e30f;

    float score = (i == START) ? 0.0f : NEGV;
    const long fb = (long)b * Tt;

    float featc = feats[(fb + 0) * 8 + i];
    for (int t = 0; t < Tt; ++t) {
        float featn = (t + 1 < Tt) ? feats[(fb + t + 1) * 8 + i] : 0.f;
        float best = -3.4e38f;
        int bp = 0;
        #pragma unroll
        for (int j = 0; j < 7; ++j) {
            float sj = __shfl(score, base | j, 64);
            float m = sj + tr[j];
            if (m > best) { best = m; bp = j; }   // strict > : first-tie like argmax
        }
        if (i < 7) score = best + featc;
        unsigned v = (i < 7) ? ((unsigned)bp << (3 * i)) : 0u;
        v |= __shfl_xor(v, 1, 64);
        v |= __shfl_xor(v, 2, 64);
        v |= __shfl_xor(v, 4, 64);
        if (i == 0) bptrw[(long)t * Bb + b] = v;
        featc = featn;
    }

    float bestv = score;
    int bt = 0;
    #pragma unroll
    for (int j = 1; j < 7; ++j) {
        float sj = __shfl(score, base | j, 64);
        if (i == 0 && sj > bestv) { bestv = sj; bt = j; }
    }
    if (i == 0) {
        best_score[b] = bestv;
        best_tag[b]   = bt;
    }
}

// ---------------------------------------------------------------------------
// Backtrace: tags[t-1] = bptr[t][tags[t]]  (bptr stored [T][B]: coalesced)
// ---------------------------------------------------------------------------
__global__ __launch_bounds__(128) void backtrack(
    const unsigned int* __restrict__ bptrw,
    const int* __restrict__ best_tag,
    float* __restrict__ out_tags)   // d_out + 128, [B,T]
{
    const int b = threadIdx.x;
    if (b >= Bb) return;
    const long fb = (long)b * Tt;
    int tag = best_tag[b];
    out_tags[fb + Tt - 1] = (float)tag;
    #pragma unroll 8
    for (int t = Tt - 1; t >= 1; --t) {
        unsigned w = bptrw[(long)t * Bb + b];
        tag = (w >> (3 * tag)) & 7;
        out_tags[fb + t - 1] = (float)tag;
    }
}

// ---------------------------------------------------------------------------
extern "C" void kernel_launch(void* const* d_in, const int* in_sizes, int n_in,
                              void* d_out, int out_size, void* d_ws, size_t ws_size,
                              hipStream_t stream)
{
    const int*   sent    = (const int*)  d_in[0];
    const float* mask    = (const float*)d_in[1];
    const float* emb     = (const float*)d_in[2];
    const float* h0      = (const float*)d_in[3];
    const float* c0      = (const float*)d_in[4];
    const float* w_ih_l0 = (const float*)d_in[5];
    const float* w_hh_l0 = (const float*)d_in[6];
    const float* b_l0    = (const float*)d_in[7];
    const float* w_ih_l1 = (const float*)d_in[8];
    const float* w_hh_l1 = (const float*)d_in[9];
    const float* b_l1    = (const float*)d_in[10];
    const float* w_ih_l2 = (const float*)d_in[11];
    const float* w_hh_l2 = (const float*)d_in[12];
    const float* b_l2    = (const float*)d_in[13];
    const float* w_tag   = (const float*)d_in[14];
    const float* b_tag   = (const float*)d_in[15];
    const float* trans   = (const float*)d_in[16];

    float* out = (float*)d_out;

    char* ws = (char*)d_ws;
    const long xg_bytes = (long)Mrows * Ncols * 4;        // 104,857,600
    const long xa_bytes = (long)Mrows * 100 * 4;          //  26,214,400
    float*    xg    = (float*)(ws);
    float*    xa    = (float*)(ws + xg_bytes);
    float*    xb    = (float*)(ws + xg_bytes + xa_bytes);
    float*    feats = (float*)(ws + xg_bytes + 2 * xa_bytes);
    unsigned* bptrw = (unsigned*)(ws + xg_bytes + 2 * xa_bytes + (long)Mrows * 8 * 4);
    int*      btag  = (int*)(ws + xg_bytes + 2 * xa_bytes + (long)Mrows * 8 * 4 + (long)Bb * Tt * 4);

    dim3 gridG(Mrows / 64, (Ncols + 63) / 64);

    // layer 0 (embedding gathered inside the GEMM)
    gemm_xg<true><<<gridG, 256, 0, stream>>>(emb, sent, w_ih_l0, b_l0, xg, Mrows, Ncols, 300);
    lstm_scan<<<256, 256, 0, stream>>>(xg, w_hh_l0, h0 + 0 * Bb * Hh, c0 + 0 * Bb * Hh, xa);

    // layer 1
    gemm_xg<false><<<gridG, 256, 0, stream>>>(xa, nullptr, w_ih_l1, b_l1, xg, Mrows, Ncols, 100);
    lstm_scan<<<256, 256, 0, stream>>>(xg, w_hh_l1, h0 + 2 * Bb * Hh, c0 + 2 * Bb * Hh, xb);

    // layer 2
    gemm_xg<false><<<gridG, 256, 0, stream>>>(xb, nullptr, w_ih_l2, b_l2, xg, Mrows, Ncols, 100);
    lstm_scan<<<256, 256, 0, stream>>>(xg, w_hh_l2, h0 + 4 * Bb * Hh, c0 + 4 * Bb * Hh, xa);

    // tag projection + viterbi + backtrace
    feats_kernel<<<Mrows * 8 / 256, 256, 0, stream>>>(xa, w_tag, b_tag, mask, feats);
    viterbi_fwd<<<Bb / 8, 64, 0, stream>>>(feats, trans, bptrw, out, btag);
    backtrack<<<1, 128, 0, stream>>>(bptrw, btag, out + Bb);
}